// Round 4
// baseline (959.522 us; speedup 1.0000x reference)
//
#include <hip/hip_runtime.h>

#define S_LEN 2048
#define NB 2
#define NH 32
#define NKV 8
#define HD 128
#define HID 4096
#define NQKV 6144

using bf16x8 = __attribute__((ext_vector_type(8))) __bf16;
using f32x4  = __attribute__((ext_vector_type(4))) float;

__device__ __forceinline__ ushort f2b(float f) {
  uint u = __builtin_bit_cast(uint, f);
  u += 0x7fffu + ((u >> 16) & 1u);
  return (ushort)(u >> 16);
}
__device__ __forceinline__ float b2f(ushort h) {
  uint u = ((uint)h) << 16;
  return __builtin_bit_cast(float, u);
}

__device__ __forceinline__ uint cvt_pk_bf16(float lo, float hi) {
  uint r;
  asm("v_cvt_pk_bf16_f32 %0, %1, %2" : "=v"(r) : "v"(lo), "v"(hi));
  return r;
}

__device__ __forceinline__ void gld16(const void* g, void* l) {
  __builtin_amdgcn_global_load_lds((const __attribute__((address_space(1))) void*)g,
                                   (__attribute__((address_space(3))) void*)l, 16, 0, 0);
}

__device__ __forceinline__ void stc(float* C, size_t i, float v)  { C[i] = v; }
__device__ __forceinline__ void stc(ushort* C, size_t i, float v) { C[i] = f2b(v); }

// ---------------- f32 -> bf16 elementwise ----------------
__global__ void cvt_bf16(const float* __restrict__ src, ushort* __restrict__ dst, int n) {
  int i = (blockIdx.x * 256 + threadIdx.x) * 4;
  if (i < n) {
    float4 v = *(const float4*)(src + i);
    *(ushort4*)(dst + i) = make_ushort4(f2b(v.x), f2b(v.y), f2b(v.z), f2b(v.w));
  }
}

// ---------------- f32 [R][C] -> bf16 [C][R] transpose (padded tile, conflict-free) ----
__global__ void trans_f32_bf16(const float* __restrict__ src, ushort* __restrict__ dst,
                               int R, int C) {
  __shared__ float tile[32][33];
  const int c0 = blockIdx.x * 32, r0 = blockIdx.y * 32;
  const int x = threadIdx.x, y = threadIdx.y;  // block (32,8)
#pragma unroll
  for (int i = 0; i < 32; i += 8)
    tile[y + i][x] = src[(size_t)(r0 + y + i) * C + (c0 + x)];
  __syncthreads();
#pragma unroll
  for (int i = 0; i < 32; i += 8)
    dst[(size_t)(c0 + y + i) * R + (r0 + x)] = f2b(tile[x][y + i]);
}

// ================= pipelined 128x256 bf16 NT GEMM =================
// C[M][N] = A[M][K] * Bt[N][K]^T. 512 threads = 8 waves (2M x 4N), BK=32,
// per-wave C sub-tile 64x64 (acc[4][4] = 64 VGPR -> <=128 VGPR, 2 blocks/CU).
// LDS 48 KiB: double-buffered A[128][32] + B[256][32], 16B-chunk XOR swizzle
// (chunk ^= row&3) -> conflict-free ds_read_b128 (8 lanes/bank-quad exactly).
// Staging: linear global_load_lds dest + INVERSE-swizzled global source (#21).
// Schedule per iteration (1 K-tile): stage ALL of tile t+1 -> buf^1 (3 glds),
// then 4 quadrants of {4 ds_read_b128 + 4 MFMA} from buf, then ONE
// vmcnt(0) + raw s_barrier. Stages never touch the buffer being read
// (disjoint by construction), loads get a full iteration of latency slack,
// and no compiler-forced full drain (__syncthreads) exists in the loop.
__device__ __forceinline__ void stage_panel(const ushort* __restrict__ src, int ld,
                                            int row0, int kt, ushort* dst,
                                            int nchunks, int wave, int lane) {
  for (int cb = wave * 64; cb < nchunks; cb += 512) {
    const int c = cb + lane;
    const int row = c >> 2;
    const int cg = (c & 3) ^ (row & 3);  // inverse-swizzled global k-chunk
    gld16(src + (size_t)(row0 + row) * ld + kt + cg * 8, dst + cb * 8);
  }
}

template <typename OutT>
__global__ __launch_bounds__(512, 4) void gemm_np(const ushort* __restrict__ A,
                                                  const ushort* __restrict__ Bt,
                                                  OutT* __restrict__ C,
                                                  int M, int Ncol, int K,
                                                  int lda, int ldb) {
  __shared__ ushort As[2][128 * 32];
  __shared__ ushort Bs[2][256 * 32];
  const int tid = threadIdx.x, wave = tid >> 6, lane = tid & 63;
  const int lr = lane & 15, lg = lane >> 4;
  const int wm = wave >> 2, wn = wave & 3;

  // bijective XCD-aware swizzle (m204 variant)
  const int gx = gridDim.x;
  const int nwg = gx * gridDim.y;
  const int orig = blockIdx.y * gx + blockIdx.x;
  const int q8 = nwg >> 3, r8 = nwg & 7, xcd = orig & 7, loc = orig >> 3;
  const int wg = (xcd < r8 ? xcd * (q8 + 1) : r8 * (q8 + 1) + (xcd - r8) * q8) + loc;
  const int n0 = (wg % gx) * 256, m0 = (wg / gx) * 128;

  f32x4 acc[4][4];
#pragma unroll
  for (int i = 0; i < 4; ++i)
#pragma unroll
    for (int j = 0; j < 4; ++j) acc[i][j] = (f32x4){0.f, 0.f, 0.f, 0.f};

  // per-lane fragment offset: row lr (within a 16-row frag), k-chunk lg,
  // swizzled. row&3 == lr&3 since all fragment row bases are multiples of 16.
  const int foff = lr * 32 + ((lg ^ (lr & 3)) << 3);
  const int NT = K >> 5;

  // prologue: tile 0 -> buf0
  stage_panel(A,  lda, m0, 0, As[0], 512, wave, lane);
  stage_panel(Bt, ldb, n0, 0, Bs[0], 1024, wave, lane);
  asm volatile("s_waitcnt vmcnt(0)" ::: "memory");
  __builtin_amdgcn_s_barrier();

  for (int it = 0; it < NT; ++it) {
    const int buf = it & 1;
    const bool more = (it + 1 < NT);
    if (more) {  // stage tile it+1 into the buffer NOT being read
      stage_panel(A,  lda, m0, (it + 1) << 5, As[buf ^ 1], 512, wave, lane);
      stage_panel(Bt, ldb, n0, (it + 1) << 5, Bs[buf ^ 1], 1024, wave, lane);
    }
    const ushort* Ap = As[buf] + wm * (64 * 32);
    const ushort* Bp = Bs[buf] + wn * (64 * 32);
#pragma unroll
    for (int q = 0; q < 4; ++q) {
      const int qm = q & 1, qn = q >> 1;
      bf16x8 af[2], bfr[2];
#pragma unroll
      for (int f = 0; f < 2; ++f)
        af[f] = *(const bf16x8*)(Ap + (qm * 2 + f) * (16 * 32) + foff);
#pragma unroll
      for (int g = 0; g < 2; ++g)
        bfr[g] = *(const bf16x8*)(Bp + (qn * 2 + g) * (16 * 32) + foff);
      __builtin_amdgcn_s_setprio(1);
#pragma unroll
      for (int f = 0; f < 2; ++f)
#pragma unroll
        for (int g = 0; g < 2; ++g)
          acc[qm * 2 + f][qn * 2 + g] = __builtin_amdgcn_mfma_f32_16x16x32_bf16(
              af[f], bfr[g], acc[qm * 2 + f][qn * 2 + g], 0, 0, 0);
      __builtin_amdgcn_s_setprio(0);
    }
    if (more) {  // single gate per K-tile: stages landed + all waves' reads done
      asm volatile("s_waitcnt vmcnt(0)" ::: "memory");
      __builtin_amdgcn_s_barrier();
    }
  }

  // epilogue: per-wave 64x64 C sub-tile
#pragma unroll
  for (int i = 0; i < 4; ++i)
#pragma unroll
    for (int j = 0; j < 4; ++j)
#pragma unroll
      for (int r = 0; r < 4; ++r) {
        const int row = m0 + wm * 64 + i * 16 + lg * 4 + r;
        const int col = n0 + wn * 64 + j * 16 + lr;
        stc(C, (size_t)row * Ncol + col, acc[i][j][r]);
      }
}

// ---------------- RoPE in-place on q/k heads of qkv (bf16) ----------------
__global__ __launch_bounds__(256) void rope_qk(ushort* __restrict__ qkv) {
  int t = blockIdx.x * 256 + threadIdx.x;
  const int i = t & 63;
  t >>= 6;
  const int head  = t % (NH + NKV);
  const int token = t / (NH + NKV);
  const int s = token & (S_LEN - 1);
  const size_t base = (size_t)token * NQKV + (head < NH ? head * HD : HID + (head - NH) * HD);
  const float x1 = b2f(qkv[base + i]);
  const float x2 = b2f(qkv[base + 64 + i]);
  const float invf = exp2f(-(float)i * 0.2076205059304602f);  // 10000^(-i/64)
  const float fr = (float)s * invf;
  float cs, sn;
  sincosf(fr, &sn, &cs);  // sincosf writes SIN first, COS second
  float o1 = x1 * cs - x2 * sn;
  float o2 = x2 * cs + x1 * sn;
  if (head < NH) {
    o1 *= 0.08838834764831845f;  // 1/sqrt(128) pre-applied to Q
    o2 *= 0.08838834764831845f;
  }
  qkv[base + i]      = f2b(o1);
  qkv[base + 64 + i] = f2b(o2);
}

// ---------------- V: qkv[token][5120+kv*128+d] -> Vt[b*8+kv][d][s] ----------------
__global__ void vtrans(const ushort* __restrict__ qkv, ushort* __restrict__ Vt) {
  __shared__ ushort tile[32][33];
  const int dt = blockIdx.x * 32, st = blockIdx.y * 32, bk = blockIdx.z;
  const int b = bk >> 3, kv = bk & 7;
  const int x = threadIdx.x, y = threadIdx.y;  // (32,8)
#pragma unroll
  for (int i = 0; i < 32; i += 8)
    tile[y + i][x] =
        qkv[(size_t)(b * S_LEN + st + y + i) * NQKV + 5120 + kv * HD + dt + x];
  __syncthreads();
#pragma unroll
  for (int i = 0; i < 32; i += 8)
    Vt[((size_t)bk * HD + dt + y + i) * S_LEN + st + x] = tile[x][y + i];
}

// ---------------- flash attention v3 (unchanged from passing R2) ----------------
__global__ __launch_bounds__(256) void attn_fa(ushort* __restrict__ qkv,
                                               const ushort* __restrict__ Vt) {
  const int lin = blockIdx.x + 32 * blockIdx.y + 256 * blockIdx.z;
  const int swz = (lin & 7) * 64 + (lin >> 3);
  const int qp = swz & 31;
  const int g  = swz >> 5;
  const int kvh = g & 7;
  const int b   = g >> 3;

  const int wid  = threadIdx.x >> 6;
  const int lane = threadIdx.x & 63;
  const int lr = lane & 15, lg = lane >> 4;
  const int h  = kvh * 4 + wid;

  const ushort* K = qkv + (size_t)(b * S_LEN) * NQKV + HID + kvh * HD;
  const ushort* V = Vt + (size_t)(b * NKV + kvh) * (HD * S_LEN);

  __shared__ ushort P[4][2][16 * 40];  // [wave][qtile][row][k padded 32->40]

  for (int seg = 0; seg < 2; ++seg) {
    const int qt = seg ? (63 - qp) : qp;
    const int q0 = qt * 32;
    const ushort* Q = qkv + (size_t)(b * S_LEN + q0) * NQKV + h * HD;

    bf16x8 qf[2][4];
#pragma unroll
    for (int t = 0; t < 2; ++t)
#pragma unroll
      for (int kb = 0; kb < 4; ++kb)
        qf[t][kb] = *(const bf16x8*)(Q + (size_t)(t * 16 + lr) * NQKV + kb * 32 + lg * 8);

    f32x4 o[2][8];
#pragma unroll
    for (int t = 0; t < 2; ++t)
#pragma unroll
      for (int c = 0; c < 8; ++c) o[t][c] = (f32x4){0.f, 0.f, 0.f, 0.f};
    float mi[2]  = {-1e30f, -1e30f};
    float lip[2] = {0.f, 0.f};

    for (int k0 = 0; k0 <= q0; k0 += 32) {
      bf16x8 kf[2][4];
#pragma unroll
      for (int kb = 0; kb < 4; ++kb) {
        kf[0][kb] = *(const bf16x8*)(K + (size_t)(k0 + lr) * NQKV + kb * 32 + lg * 8);
        kf[1][kb] = *(const bf16x8*)(K + (size_t)(k0 + 16 + lr) * NQKV + kb * 32 + lg * 8);
      }
      bf16x8 vf[8];
#pragma unroll
      for (int c = 0; c < 8; ++c)
        vf[c] = *(const bf16x8*)(V + (size_t)(c * 16 + lr) * S_LEN + k0 + lg * 8);

      f32x4 s[2][2];
#pragma unroll
      for (int t = 0; t < 2; ++t)
#pragma unroll
        for (int u = 0; u < 2; ++u) s[t][u] = (f32x4){0.f, 0.f, 0.f, 0.f};

      __builtin_amdgcn_s_setprio(1);
#pragma unroll
      for (int kb = 0; kb < 4; ++kb) {
        s[0][0] = __builtin_amdgcn_mfma_f32_16x16x32_bf16(kf[0][kb], qf[0][kb], s[0][0], 0, 0, 0);
        s[1][0] = __builtin_amdgcn_mfma_f32_16x16x32_bf16(kf[0][kb], qf[1][kb], s[1][0], 0, 0, 0);
        s[0][1] = __builtin_amdgcn_mfma_f32_16x16x32_bf16(kf[1][kb], qf[0][kb], s[0][1], 0, 0, 0);
        s[1][1] = __builtin_amdgcn_mfma_f32_16x16x32_bf16(kf[1][kb], qf[1][kb], s[1][1], 0, 0, 0);
      }
      __builtin_amdgcn_s_setprio(0);

      if (k0 == q0) {
#pragma unroll
        for (int t = 0; t < 2; ++t)
#pragma unroll
          for (int u = 0; u < 2; ++u)
#pragma unroll
            for (int r = 0; r < 4; ++r)
              if (u * 16 + lg * 4 + r > t * 16 + lr) s[t][u][r] = -1e30f;
      }

      float pm[2];
#pragma unroll
      for (int t = 0; t < 2; ++t) {
        float a = fmaxf(fmaxf(s[t][0][0], s[t][0][1]), fmaxf(s[t][0][2], s[t][0][3]));
        float c = fmaxf(fmaxf(s[t][1][0], s[t][1][1]), fmaxf(s[t][1][2], s[t][1][3]));
        pm[t] = fmaxf(a, c);
      }

      if (__any((pm[0] > mi[0] + 8.f) || (pm[1] > mi[1] + 8.f))) {
#pragma unroll
        for (int t = 0; t < 2; ++t) {
          float m = pm[t];
          m = fmaxf(m, __shfl_xor(m, 16));
          m = fmaxf(m, __shfl_xor(m, 32));
          const float mn = fmaxf(mi[t], m);
          const float al = __expf(mi[t] - mn);
          mi[t] = mn;
          lip[t] *= al;
#pragma unroll
          for (int r = 0; r < 4; ++r) {
            const float ar = __shfl(al, lg * 4 + r);
#pragma unroll
            for (int c = 0; c < 8; ++c) o[t][c][r] *= ar;
          }
        }
      }

#pragma unroll
      for (int t = 0; t < 2; ++t) {
        float p[2][4];
#pragma unroll
        for (int u = 0; u < 2; ++u)
#pragma unroll
          for (int r = 0; r < 4; ++r) p[u][r] = __expf(s[t][u][r] - mi[t]);
        lip[t] += ((p[0][0] + p[0][1]) + (p[0][2] + p[0][3])) +
                  ((p[1][0] + p[1][1]) + (p[1][2] + p[1][3]));
        ushort* Pw = &P[wid][t][0];
#pragma unroll
        for (int u = 0; u < 2; ++u) {
          const uint w0 = cvt_pk_bf16(p[u][0], p[u][1]);
          const uint w1 = cvt_pk_bf16(p[u][2], p[u][3]);
          *(uint2*)(Pw + lr * 40 + u * 16 + lg * 4) = make_uint2(w0, w1);
        }
      }
      const bf16x8 pa0 = *(const bf16x8*)(&P[wid][0][0] + lr * 40 + lg * 8);
      const bf16x8 pa1 = *(const bf16x8*)(&P[wid][1][0] + lr * 40 + lg * 8);

      __builtin_amdgcn_s_setprio(1);
#pragma unroll
      for (int c = 0; c < 8; ++c) {
        o[0][c] = __builtin_amdgcn_mfma_f32_16x16x32_bf16(pa0, vf[c], o[0][c], 0, 0, 0);
        o[1][c] = __builtin_amdgcn_mfma_f32_16x16x32_bf16(pa1, vf[c], o[1][c], 0, 0, 0);
      }
      __builtin_amdgcn_s_setprio(0);
    }

    float linv[2];
#pragma unroll
    for (int t = 0; t < 2; ++t) {
      float rt = lip[t];
      rt += __shfl_xor(rt, 16);
      rt += __shfl_xor(rt, 32);
      linv[t] = 1.f / rt;
    }
#pragma unroll
    for (int t = 0; t < 2; ++t) {
#pragma unroll
      for (int r = 0; r < 4; ++r) {
        const float ir = __shfl(linv[t], lg * 4 + r);
        const size_t row = (size_t)(b * S_LEN + q0 + t * 16 + lg * 4 + r) * NQKV + h * HD;
#pragma unroll
        for (int c = 0; c < 8; ++c) qkv[row + c * 16 + lr] = f2b(o[t][c][r] * ir);
      }
    }
  }
}

extern "C" void kernel_launch(void* const* d_in, const int* in_sizes, int n_in,
                              void* d_out, int out_size, void* d_ws, size_t ws_size,
                              hipStream_t stream) {
  const float* hidden = (const float*)d_in[1];
  const float* w_qkv  = (const float*)d_in[2];
  const float* w_o    = (const float*)d_in[3];
  float* out = (float*)d_out;
  char* ws = (char*)d_ws;

  // workspace layout (128 MiB):
  // R0 [0, 48 MiB)   : wqkvT bf16 [6144][4096]; after gemm1: Vt bf16 [16][128][2048]
  // R1 [48, 80 MiB)  : hb bf16 [4096][4096];    after gemm1: woT bf16 [4096][4096]
  // R2 [80, 128 MiB) : qkv bf16 [4096][6144]; rope in-place; attn into q slots
  ushort* wqkvT = (ushort*)(ws);
  ushort* Vt    = (ushort*)(ws);
  ushort* hb    = (ushort*)(ws + (48u << 20));
  ushort* woT   = (ushort*)(ws + (48u << 20));
  ushort* qkvb  = (ushort*)(ws + (80u << 20));

  // 1) weight + activation prep
  trans_f32_bf16<<<dim3(192, 128), dim3(32, 8), 0, stream>>>(w_qkv, wqkvT, HID, NQKV);
  cvt_bf16<<<16384, 256, 0, stream>>>(hidden, hb, NB * S_LEN * HID);
  // 2) qkv = hb @ wqkvT^T  (pipelined 128x256, grid 24n x 32m = 768 blocks)
  gemm_np<ushort><<<dim3(24, 32), 512, 0, stream>>>(
      hb, wqkvT, qkvb, NB * S_LEN, NQKV, HID, HID, HID);
  // 3) RoPE in-place (q pre-scaled by 1/sqrt(D))
  rope_qk<<<40960, 256, 0, stream>>>(qkvb);
  // 4) V -> Vt[d][s]  (into dead wqkvT region)
  vtrans<<<dim3(4, 64, 16), dim3(32, 8), 0, stream>>>(qkvb, Vt);
  // 5) w_o -> woT (into dead hb region)
  trans_f32_bf16<<<dim3(128, 128), dim3(32, 8), 0, stream>>>(w_o, woT, HID, HID);
  // 6) flash attention v3: paired q-tiles {qp, 63-qp}, 512 equal-work blocks
  attn_fa<<<dim3(32, 8, 2), 256, 0, stream>>>(qkvb, Vt);
  // 7) out = attn @ woT^T  (pipelined 128x256, grid 16n x 32m = 512 blocks)
  gemm_np<float><<<dim3(16, 32), 512, 0, stream>>>(
      qkvb, woT, out, NB * S_LEN, HID, HID, NQKV, HID);
}

// Round 5
// 855.442 us; speedup vs baseline: 1.1217x; 1.1217x over previous
//
#include <hip/hip_runtime.h>

#define S_LEN 2048
#define NB 2
#define NH 32
#define NKV 8
#define HD 128
#define HID 4096
#define NQKV 6144

using bf16x8 = __attribute__((ext_vector_type(8))) __bf16;
using f32x4  = __attribute__((ext_vector_type(4))) float;

__device__ __forceinline__ ushort f2b(float f) {
  uint u = __builtin_bit_cast(uint, f);
  u += 0x7fffu + ((u >> 16) & 1u);
  return (ushort)(u >> 16);
}
__device__ __forceinline__ float b2f(ushort h) {
  uint u = ((uint)h) << 16;
  return __builtin_bit_cast(float, u);
}

__device__ __forceinline__ uint cvt_pk_bf16(float lo, float hi) {
  uint r;
  asm("v_cvt_pk_bf16_f32 %0, %1, %2" : "=v"(r) : "v"(lo), "v"(hi));
  return r;
}

__device__ __forceinline__ void gld16(const void* g, void* l) {
  __builtin_amdgcn_global_load_lds((const __attribute__((address_space(1))) void*)g,
                                   (__attribute__((address_space(3))) void*)l, 16, 0, 0);
}

__device__ __forceinline__ void stc(float* C, size_t i, float v)  { C[i] = v; }
__device__ __forceinline__ void stc(ushort* C, size_t i, float v) { C[i] = f2b(v); }

// ---------------- f32 -> bf16 elementwise ----------------
__global__ void cvt_bf16(const float* __restrict__ src, ushort* __restrict__ dst, int n) {
  int i = (blockIdx.x * 256 + threadIdx.x) * 4;
  if (i < n) {
    float4 v = *(const float4*)(src + i);
    *(ushort4*)(dst + i) = make_ushort4(f2b(v.x), f2b(v.y), f2b(v.z), f2b(v.w));
  }
}

// ---------------- f32 [R][C] -> bf16 [C][R] transpose (padded tile, conflict-free) ----
__global__ void trans_f32_bf16(const float* __restrict__ src, ushort* __restrict__ dst,
                               int R, int C) {
  __shared__ float tile[32][33];
  const int c0 = blockIdx.x * 32, r0 = blockIdx.y * 32;
  const int x = threadIdx.x, y = threadIdx.y;  // block (32,8)
#pragma unroll
  for (int i = 0; i < 32; i += 8)
    tile[y + i][x] = src[(size_t)(r0 + y + i) * C + (c0 + x)];
  __syncthreads();
#pragma unroll
  for (int i = 0; i < 32; i += 8)
    dst[(size_t)(c0 + y + i) * R + (r0 + x)] = f2b(tile[x][y + i]);
}

// ================= pipelined 128x128 bf16 NT GEMM (ring-2, BK=64) =================
// C[M][N] = A[M][K] * Bt[N][K]^T. 256 threads = 4 waves (2M x 2N), wave tile
// 64x64 (acc[4][4], 16 ds_read per 32 MFMA — the m97 ratio). BK=64, LDS = 64 KiB
// static: double-buffered A[128][64] + B[128][64].
// SCHEDULE (the R4 fix): stage tile i+1 at the TOP of iteration i, then gate
// vmcnt(8) — keeps the 8 just-issued loads in flight and only waits for tile i,
// issued one full iteration earlier (~400-600 cy of slack). Raw s_barrier (no
// __syncthreads vmcnt(0) drain) x2 per iteration.
// SWIZZLE: row of 8 16B-chunks; slot s of row r holds k-chunk kc = s ^ (r&7).
// Reads: every 16-lane quarter hits all 8 bank-quads exactly twice (2-way =
// free, m136). Writes (global_load_lds): linear dest + inverse-swizzled GLOBAL
// source (rule #21); consecutive lanes -> consecutive chunks (conflict-free).
__device__ __forceinline__ void stage_tile(const ushort* __restrict__ A,
                                           const ushort* __restrict__ Bt,
                                           int lda, int ldb, int m0, int n0, int kt,
                                           ushort* dA, ushort* dB, int wave, int lane) {
#pragma unroll
  for (int h = 0; h < 4; ++h) {
    const int cb = h * 256 + wave * 64;  // wave-uniform LDS chunk base
    const int c = cb + lane;
    const int row = c >> 3;
    const int kc = (c & 7) ^ (row & 7);  // inverse-swizzled global k-chunk
    gld16(A  + (size_t)(m0 + row) * lda + kt + kc * 8, dA + cb * 8);
    gld16(Bt + (size_t)(n0 + row) * ldb + kt + kc * 8, dB + cb * 8);
  }
}

template <typename OutT>
__global__ __launch_bounds__(256, 2) void gemm_p2(const ushort* __restrict__ A,
                                                  const ushort* __restrict__ Bt,
                                                  OutT* __restrict__ C,
                                                  int M, int Ncol, int K,
                                                  int lda, int ldb) {
  __shared__ ushort As[2][128 * 64];
  __shared__ ushort Bs[2][128 * 64];
  const int tid = threadIdx.x, wave = tid >> 6, lane = tid & 63;
  const int lr = lane & 15, lg = lane >> 4;
  const int wm = wave >> 1, wn = wave & 1;
  const int m0 = blockIdx.y * 128, n0 = blockIdx.x * 128;

  f32x4 acc[4][4];
#pragma unroll
  for (int i = 0; i < 4; ++i)
#pragma unroll
    for (int j = 0; j < 4; ++j) acc[i][j] = (f32x4){0.f, 0.f, 0.f, 0.f};

  const int NT = K >> 6;

  // prologue: tile 0 -> buf 0
  stage_tile(A, Bt, lda, ldb, m0, n0, 0, As[0], Bs[0], wave, lane);

  for (int it = 0; it < NT; ++it) {
    const int buf = it & 1;
    if (it + 1 < NT) {
      // stage tile it+1 into the buffer last read at iteration it-1 (freed by
      // the end-of-iteration barrier), then gate: keep the 8 new loads in
      // flight, wait only for tile it (issued one iteration ago).
      stage_tile(A, Bt, lda, ldb, m0, n0, (it + 1) << 6, As[buf ^ 1], Bs[buf ^ 1],
                 wave, lane);
      asm volatile("s_waitcnt vmcnt(8)" ::: "memory");
    } else {
      asm volatile("s_waitcnt vmcnt(0)" ::: "memory");
    }
    asm volatile("s_barrier" ::: "memory");  // tile it resident, wave-global

#pragma unroll
    for (int kk = 0; kk < 2; ++kk) {  // two 32-K steps of the 64-K tile
      bf16x8 af[4], bfr[4];
#pragma unroll
      for (int f = 0; f < 4; ++f) {
        const int row = wm * 64 + f * 16 + lr;
        af[f] = *(const bf16x8*)(&As[buf][row * 64 + (((kk * 4 + lg) ^ (lr & 7)) << 3)]);
      }
#pragma unroll
      for (int g = 0; g < 4; ++g) {
        const int row = wn * 64 + g * 16 + lr;
        bfr[g] = *(const bf16x8*)(&Bs[buf][row * 64 + (((kk * 4 + lg) ^ (lr & 7)) << 3)]);
      }
      __builtin_amdgcn_s_setprio(1);
#pragma unroll
      for (int f = 0; f < 4; ++f)
#pragma unroll
        for (int g = 0; g < 4; ++g)
          acc[f][g] = __builtin_amdgcn_mfma_f32_16x16x32_bf16(af[f], bfr[g], acc[f][g], 0, 0, 0);
      __builtin_amdgcn_s_setprio(0);
    }
    // all waves done reading buf before anyone stages into it next iteration
    asm volatile("s_barrier" ::: "memory");
  }

  // epilogue: per-wave 64x64 C sub-tile
#pragma unroll
  for (int f = 0; f < 4; ++f)
#pragma unroll
    for (int g = 0; g < 4; ++g)
#pragma unroll
      for (int r = 0; r < 4; ++r) {
        const int row = m0 + wm * 64 + f * 16 + lg * 4 + r;
        const int col = n0 + wn * 64 + g * 16 + lr;
        stc(C, (size_t)row * Ncol + col, acc[f][g][r]);
      }
}

// ---------------- RoPE in-place on q/k heads of qkv (bf16) ----------------
__global__ __launch_bounds__(256) void rope_qk(ushort* __restrict__ qkv) {
  int t = blockIdx.x * 256 + threadIdx.x;
  const int i = t & 63;
  t >>= 6;
  const int head  = t % (NH + NKV);
  const int token = t / (NH + NKV);
  const int s = token & (S_LEN - 1);
  const size_t base = (size_t)token * NQKV + (head < NH ? head * HD : HID + (head - NH) * HD);
  const float x1 = b2f(qkv[base + i]);
  const float x2 = b2f(qkv[base + 64 + i]);
  const float invf = exp2f(-(float)i * 0.2076205059304602f);  // 10000^(-i/64)
  const float fr = (float)s * invf;
  float cs, sn;
  sincosf(fr, &sn, &cs);  // sincosf writes SIN first, COS second
  float o1 = x1 * cs - x2 * sn;
  float o2 = x2 * cs + x1 * sn;
  if (head < NH) {
    o1 *= 0.08838834764831845f;  // 1/sqrt(128) pre-applied to Q
    o2 *= 0.08838834764831845f;
  }
  qkv[base + i]      = f2b(o1);
  qkv[base + 64 + i] = f2b(o2);
}

// ---------------- V: qkv[token][5120+kv*128+d] -> Vt[b*8+kv][d][s] ----------------
__global__ void vtrans(const ushort* __restrict__ qkv, ushort* __restrict__ Vt) {
  __shared__ ushort tile[32][33];
  const int dt = blockIdx.x * 32, st = blockIdx.y * 32, bk = blockIdx.z;
  const int b = bk >> 3, kv = bk & 7;
  const int x = threadIdx.x, y = threadIdx.y;  // (32,8)
#pragma unroll
  for (int i = 0; i < 32; i += 8)
    tile[y + i][x] =
        qkv[(size_t)(b * S_LEN + st + y + i) * NQKV + 5120 + kv * HD + dt + x];
  __syncthreads();
#pragma unroll
  for (int i = 0; i < 32; i += 8)
    Vt[((size_t)bk * HD + dt + y + i) * S_LEN + st + x] = tile[x][y + i];
}

// ---------------- flash attention v3 (unchanged from passing R4) ----------------
__global__ __launch_bounds__(256) void attn_fa(ushort* __restrict__ qkv,
                                               const ushort* __restrict__ Vt) {
  const int lin = blockIdx.x + 32 * blockIdx.y + 256 * blockIdx.z;
  const int swz = (lin & 7) * 64 + (lin >> 3);
  const int qp = swz & 31;
  const int g  = swz >> 5;
  const int kvh = g & 7;
  const int b   = g >> 3;

  const int wid  = threadIdx.x >> 6;
  const int lane = threadIdx.x & 63;
  const int lr = lane & 15, lg = lane >> 4;
  const int h  = kvh * 4 + wid;

  const ushort* K = qkv + (size_t)(b * S_LEN) * NQKV + HID + kvh * HD;
  const ushort* V = Vt + (size_t)(b * NKV + kvh) * (HD * S_LEN);

  __shared__ ushort P[4][2][16 * 40];  // [wave][qtile][row][k padded 32->40]

  for (int seg = 0; seg < 2; ++seg) {
    const int qt = seg ? (63 - qp) : qp;
    const int q0 = qt * 32;
    const ushort* Q = qkv + (size_t)(b * S_LEN + q0) * NQKV + h * HD;

    bf16x8 qf[2][4];
#pragma unroll
    for (int t = 0; t < 2; ++t)
#pragma unroll
      for (int kb = 0; kb < 4; ++kb)
        qf[t][kb] = *(const bf16x8*)(Q + (size_t)(t * 16 + lr) * NQKV + kb * 32 + lg * 8);

    f32x4 o[2][8];
#pragma unroll
    for (int t = 0; t < 2; ++t)
#pragma unroll
      for (int c = 0; c < 8; ++c) o[t][c] = (f32x4){0.f, 0.f, 0.f, 0.f};
    float mi[2]  = {-1e30f, -1e30f};
    float lip[2] = {0.f, 0.f};

    for (int k0 = 0; k0 <= q0; k0 += 32) {
      bf16x8 kf[2][4];
#pragma unroll
      for (int kb = 0; kb < 4; ++kb) {
        kf[0][kb] = *(const bf16x8*)(K + (size_t)(k0 + lr) * NQKV + kb * 32 + lg * 8);
        kf[1][kb] = *(const bf16x8*)(K + (size_t)(k0 + 16 + lr) * NQKV + kb * 32 + lg * 8);
      }
      bf16x8 vf[8];
#pragma unroll
      for (int c = 0; c < 8; ++c)
        vf[c] = *(const bf16x8*)(V + (size_t)(c * 16 + lr) * S_LEN + k0 + lg * 8);

      f32x4 s[2][2];
#pragma unroll
      for (int t = 0; t < 2; ++t)
#pragma unroll
        for (int u = 0; u < 2; ++u) s[t][u] = (f32x4){0.f, 0.f, 0.f, 0.f};

      __builtin_amdgcn_s_setprio(1);
#pragma unroll
      for (int kb = 0; kb < 4; ++kb) {
        s[0][0] = __builtin_amdgcn_mfma_f32_16x16x32_bf16(kf[0][kb], qf[0][kb], s[0][0], 0, 0, 0);
        s[1][0] = __builtin_amdgcn_mfma_f32_16x16x32_bf16(kf[0][kb], qf[1][kb], s[1][0], 0, 0, 0);
        s[0][1] = __builtin_amdgcn_mfma_f32_16x16x32_bf16(kf[1][kb], qf[0][kb], s[0][1], 0, 0, 0);
        s[1][1] = __builtin_amdgcn_mfma_f32_16x16x32_bf16(kf[1][kb], qf[1][kb], s[1][1], 0, 0, 0);
      }
      __builtin_amdgcn_s_setprio(0);

      if (k0 == q0) {
#pragma unroll
        for (int t = 0; t < 2; ++t)
#pragma unroll
          for (int u = 0; u < 2; ++u)
#pragma unroll
            for (int r = 0; r < 4; ++r)
              if (u * 16 + lg * 4 + r > t * 16 + lr) s[t][u][r] = -1e30f;
      }

      float pm[2];
#pragma unroll
      for (int t = 0; t < 2; ++t) {
        float a = fmaxf(fmaxf(s[t][0][0], s[t][0][1]), fmaxf(s[t][0][2], s[t][0][3]));
        float c = fmaxf(fmaxf(s[t][1][0], s[t][1][1]), fmaxf(s[t][1][2], s[t][1][3]));
        pm[t] = fmaxf(a, c);
      }

      if (__any((pm[0] > mi[0] + 8.f) || (pm[1] > mi[1] + 8.f))) {
#pragma unroll
        for (int t = 0; t < 2; ++t) {
          float m = pm[t];
          m = fmaxf(m, __shfl_xor(m, 16));
          m = fmaxf(m, __shfl_xor(m, 32));
          const float mn = fmaxf(mi[t], m);
          const float al = __expf(mi[t] - mn);
          mi[t] = mn;
          lip[t] *= al;
#pragma unroll
          for (int r = 0; r < 4; ++r) {
            const float ar = __shfl(al, lg * 4 + r);
#pragma unroll
            for (int c = 0; c < 8; ++c) o[t][c][r] *= ar;
          }
        }
      }

#pragma unroll
      for (int t = 0; t < 2; ++t) {
        float p[2][4];
#pragma unroll
        for (int u = 0; u < 2; ++u)
#pragma unroll
          for (int r = 0; r < 4; ++r) p[u][r] = __expf(s[t][u][r] - mi[t]);
        lip[t] += ((p[0][0] + p[0][1]) + (p[0][2] + p[0][3])) +
                  ((p[1][0] + p[1][1]) + (p[1][2] + p[1][3]));
        ushort* Pw = &P[wid][t][0];
#pragma unroll
        for (int u = 0; u < 2; ++u) {
          const uint w0 = cvt_pk_bf16(p[u][0], p[u][1]);
          const uint w1 = cvt_pk_bf16(p[u][2], p[u][3]);
          *(uint2*)(Pw + lr * 40 + u * 16 + lg * 4) = make_uint2(w0, w1);
        }
      }
      const bf16x8 pa0 = *(const bf16x8*)(&P[wid][0][0] + lr * 40 + lg * 8);
      const bf16x8 pa1 = *(const bf16x8*)(&P[wid][1][0] + lr * 40 + lg * 8);

      __builtin_amdgcn_s_setprio(1);
#pragma unroll
      for (int c = 0; c < 8; ++c) {
        o[0][c] = __builtin_amdgcn_mfma_f32_16x16x32_bf16(pa0, vf[c], o[0][c], 0, 0, 0);
        o[1][c] = __builtin_amdgcn_mfma_f32_16x16x32_bf16(pa1, vf[c], o[1][c], 0, 0, 0);
      }
      __builtin_amdgcn_s_setprio(0);
    }

    float linv[2];
#pragma unroll
    for (int t = 0; t < 2; ++t) {
      float rt = lip[t];
      rt += __shfl_xor(rt, 16);
      rt += __shfl_xor(rt, 32);
      linv[t] = 1.f / rt;
    }
#pragma unroll
    for (int t = 0; t < 2; ++t) {
#pragma unroll
      for (int r = 0; r < 4; ++r) {
        const float ir = __shfl(linv[t], lg * 4 + r);
        const size_t row = (size_t)(b * S_LEN + q0 + t * 16 + lg * 4 + r) * NQKV + h * HD;
#pragma unroll
        for (int c = 0; c < 8; ++c) qkv[row + c * 16 + lr] = f2b(o[t][c][r] * ir);
      }
    }
  }
}

extern "C" void kernel_launch(void* const* d_in, const int* in_sizes, int n_in,
                              void* d_out, int out_size, void* d_ws, size_t ws_size,
                              hipStream_t stream) {
  const float* hidden = (const float*)d_in[1];
  const float* w_qkv  = (const float*)d_in[2];
  const float* w_o    = (const float*)d_in[3];
  float* out = (float*)d_out;
  char* ws = (char*)d_ws;

  // workspace layout (128 MiB):
  // R0 [0, 48 MiB)   : wqkvT bf16 [6144][4096]; after gemm1: Vt bf16 [16][128][2048]
  // R1 [48, 80 MiB)  : hb bf16 [4096][4096];    after gemm1: woT bf16 [4096][4096]
  // R2 [80, 128 MiB) : qkv bf16 [4096][6144]; rope in-place; attn into q slots
  ushort* wqkvT = (ushort*)(ws);
  ushort* Vt    = (ushort*)(ws);
  ushort* hb    = (ushort*)(ws + (48u << 20));
  ushort* woT   = (ushort*)(ws + (48u << 20));
  ushort* qkvb  = (ushort*)(ws + (80u << 20));

  // 1) weight + activation prep
  trans_f32_bf16<<<dim3(192, 128), dim3(32, 8), 0, stream>>>(w_qkv, wqkvT, HID, NQKV);
  cvt_bf16<<<16384, 256, 0, stream>>>(hidden, hb, NB * S_LEN * HID);
  // 2) qkv = hb @ wqkvT^T  (ring-2 BK=64 pipelined 128x128)
  gemm_p2<ushort><<<dim3(48, 32), 256, 0, stream>>>(
      hb, wqkvT, qkvb, NB * S_LEN, NQKV, HID, HID, HID);
  // 3) RoPE in-place (q pre-scaled by 1/sqrt(D))
  rope_qk<<<40960, 256, 0, stream>>>(qkvb);
  // 4) V -> Vt[d][s]  (into dead wqkvT region)
  vtrans<<<dim3(4, 64, 16), dim3(32, 8), 0, stream>>>(qkvb, Vt);
  // 5) w_o -> woT (into dead hb region)
  trans_f32_bf16<<<dim3(128, 128), dim3(32, 8), 0, stream>>>(w_o, woT, HID, HID);
  // 6) flash attention v3: paired q-tiles {qp, 63-qp}, 512 equal-work blocks
  attn_fa<<<dim3(32, 8, 2), 256, 0, stream>>>(qkvb, Vt);
  // 7) out = attn @ woT^T  (ring-2 BK=64 pipelined 128x128)
  gemm_p2<float><<<dim3(32, 32), 256, 0, stream>>>(
      qkvb, woT, out, NB * S_LEN, HID, HID, NQKV, HID);
}